// Round 4
// baseline (302.067 us; speedup 1.0000x reference)
//
#include <hip/hip_runtime.h>
#include <hip/hip_bf16.h>
#include <math.h>

#define NEG_SLOPE 0.2f
// wave-internal LDS ordering: each wave owns a private LDS slice, so a plain
// lgkmcnt drain orders its own ds ops; no __syncthreads (degrees diverge).
#define LDS_FENCE() asm volatile("s_waitcnt lgkmcnt(0)" ::: "memory")

// ---------- small utils ----------
__global__ void k_zero_i32(int* __restrict__ p, int n) {
    int i = blockIdx.x * blockDim.x + threadIdx.x;
    if (i < n) p[i] = 0;
}

// ---------- CSR build over dst ----------
__global__ void k_count(const int* __restrict__ ei, int E, int N, int* __restrict__ counts) {
    int e = blockIdx.x * blockDim.x + threadIdx.x;
    int Etot = E + N;
    if (e >= Etot) return;
    int d = (e < E) ? ei[E + e] : (e - E);
    atomicAdd(&counts[d], 1);
}

// single-block shuffle scan: 1024 threads, wave-scan + 16-wave prefix
__global__ __launch_bounds__(1024) void k_scan(const int* __restrict__ counts,
                                               int* __restrict__ rowptr, int N) {
    __shared__ int wsums[16];
    __shared__ int wpref[17];
    int lane = threadIdx.x & 63, wave = threadIdx.x >> 6;
    int carry = 0;
    for (int base = 0; base < N; base += 1024) {
        int i = base + threadIdx.x;
        int v = (i < N) ? counts[i] : 0;
        int x = v;
#pragma unroll
        for (int off = 1; off < 64; off <<= 1) {
            int t = __shfl_up(x, off);
            if (lane >= off) x += t;
        }
        if (lane == 63) wsums[wave] = x;
        __syncthreads();
        if (threadIdx.x == 0) {
            int acc = 0;
#pragma unroll
            for (int w = 0; w < 16; ++w) { wpref[w] = acc; acc += wsums[w]; }
            wpref[16] = acc;
        }
        __syncthreads();
        if (i < N) rowptr[i] = carry + wpref[wave] + x - v;
        carry += wpref[16];
        __syncthreads();
    }
    if (threadIdx.x == 0) rowptr[N] = carry;
}

__global__ void k_copy_i32(const int* __restrict__ src, int* __restrict__ dst, int n) {
    int i = blockIdx.x * blockDim.x + threadIdx.x;
    if (i < n) dst[i] = src[i];
}

__global__ void k_fill_csr(const int* __restrict__ ei, int E, int N,
                           int* __restrict__ cursor, int* __restrict__ col) {
    int e = blockIdx.x * blockDim.x + threadIdx.x;
    int Etot = E + N;
    if (e >= Etot) return;
    int s, d;
    if (e < E) { s = ei[e]; d = ei[E + e]; } else { s = d = e - E; }
    int pos = atomicAdd(&cursor[d], 1);
    col[pos] = s;
}

// ---------- tiled GEMM: C[n,j] = sum_k X[n,k]*W[k,j], M=256 cols ----------
// block: 32 rows x 256 cols; wave ry owns rows ry*8..+7 (xs reads broadcast),
// thread cx owns cols 4cx..4cx+3. W float4 reused 4x via L1 across waves.
template <int K>
__global__ __launch_bounds__(256) void k_gemm_t(const float* __restrict__ X,
                                                const float* __restrict__ W,
                                                float* __restrict__ C, int N) {
    __shared__ float xs[32][K];
    int t = threadIdx.x;
    int n0 = blockIdx.x * 32;
    for (int idx = t; idx < 32 * K; idx += 256) {
        int r = idx / K, k = idx % K;
        int n = n0 + r;
        xs[r][k] = (n < N) ? X[(size_t)n * K + k] : 0.f;
    }
    __syncthreads();
    int cx = t & 63, ry = t >> 6;
    float4 acc[8] = {};
    const float* Wp = W + cx * 4;
#pragma unroll 2
    for (int k = 0; k < K; ++k) {
        float4 w4 = *(const float4*)(Wp + (size_t)k * 256);
#pragma unroll
        for (int rr = 0; rr < 8; ++rr) {
            float xv = xs[ry * 8 + rr][k];
            acc[rr].x = fmaf(xv, w4.x, acc[rr].x);
            acc[rr].y = fmaf(xv, w4.y, acc[rr].y);
            acc[rr].z = fmaf(xv, w4.z, acc[rr].z);
            acc[rr].w = fmaf(xv, w4.w, acc[rr].w);
        }
    }
#pragma unroll
    for (int rr = 0; rr < 8; ++rr) {
        int n = n0 + ry * 8 + rr;
        if (n < N) *(float4*)(C + (size_t)n * 256 + cx * 4) = acc[rr];
    }
}

// ---------- layer-1 attention logits: thread per (n,h), ch=16 ----------
__global__ void k_logits1(const float* __restrict__ H, const float* __restrict__ a_src,
                          const float* __restrict__ a_dst, float* __restrict__ als,
                          float* __restrict__ ald, int NH) {
    int i = blockIdx.x * blockDim.x + threadIdx.x;
    if (i >= NH) return;
    int h = i & 15;
    const float4* hp = (const float4*)(H + (size_t)i * 16);
    const float4* as = (const float4*)(a_src + h * 16);
    const float4* ad = (const float4*)(a_dst + h * 16);
    float s = 0.f, d = 0.f;
#pragma unroll
    for (int q = 0; q < 4; ++q) {
        float4 hv = hp[q], sv = as[q], dv = ad[q];
        s += hv.x * sv.x + hv.y * sv.y + hv.z * sv.z + hv.w * sv.w;
        d += hv.x * dv.x + hv.y * dv.y + hv.z * dv.z + hv.w * dv.w;
    }
    als[i] = s;
    ald[i] = d;
}

// ---------- layer-2 attention logits: wave per node, D=256 ----------
__global__ __launch_bounds__(256) void k_logits2(const float* __restrict__ H,
                                                 const float* __restrict__ a_src,
                                                 const float* __restrict__ a_dst,
                                                 float* __restrict__ als,
                                                 float* __restrict__ ald, int N) {
    int wave = threadIdx.x >> 6, lane = threadIdx.x & 63;
    int n = blockIdx.x * 4 + wave;
    if (n >= N) return;
    float4 hv = *(const float4*)(H + (size_t)n * 256 + lane * 4);
    float4 sv = *(const float4*)(a_src + lane * 4);
    float4 dv = *(const float4*)(a_dst + lane * 4);
    float s = hv.x * sv.x + hv.y * sv.y + hv.z * sv.z + hv.w * sv.w;
    float d = hv.x * dv.x + hv.y * dv.y + hv.z * dv.z + hv.w * dv.w;
#pragma unroll
    for (int off = 32; off >= 1; off >>= 1) {
        s += __shfl_xor(s, off);
        d += __shfl_xor(d, off);
    }
    if (lane == 0) { als[n] = s; ald[n] = d; }
}

// ---------- fused GAT gather, 1 head, channel-half split ----------
// grid (nodes/4, 2); wave per node, lane owns 2 channels of half hf (float2).
// phase hf=0 blocks dispatch first: active H footprint 5MB -> L2-resident.
__global__ __launch_bounds__(256) void k_gather_h1(
    const int* __restrict__ rowptr, const int* __restrict__ col,
    const float* __restrict__ H, const float* __restrict__ als,
    const float* __restrict__ ald, const float* __restrict__ bias,
    float* __restrict__ out, int N) {
    __shared__ float2 sw[4][64];
    int wave = threadIdx.x >> 6, lane = threadIdx.x & 63;
    int n = blockIdx.x * 4 + wave;
    if (n >= N) return;
    int hf = blockIdx.y;
    int coff = hf * 128 + lane * 2;
    int start = rowptr[n], end = rowptr[n + 1];
    float aldv = ald[n];
    float2 acc = {0.f, 0.f};
    float swsum = 0.f;
    const float* Hh = H + coff;
    for (int base = start; base < end; base += 64) {
        int len = min(64, end - base);
        int s = 0;
        float w = 0.f;
        if (lane < len) {
            s = col[base + lane];
            float v = als[s] + aldv;
            v = v >= 0.f ? v : NEG_SLOPE * v;
            w = __expf(v);
        }
        swsum += w;
        sw[wave][lane] = make_float2(__int_as_float(s), w);
        LDS_FENCE();
#pragma unroll 4
        for (int e = 0; e < len; ++e) {
            float2 p = sw[wave][e];
            int se = __float_as_int(p.x);
            float we = p.y;
            float2 hv = *(const float2*)(Hh + (size_t)se * 256);
            acc.x = fmaf(we, hv.x, acc.x);
            acc.y = fmaf(we, hv.y, acc.y);
        }
        LDS_FENCE();
    }
#pragma unroll
    for (int off = 32; off >= 1; off >>= 1) swsum += __shfl_xor(swsum, off);
    float inv = 1.0f / swsum;
    float2 b2v = *(const float2*)(bias + coff);
    float2 r;
    r.x = fmaf(acc.x, inv, b2v.x);
    r.y = fmaf(acc.y, inv, b2v.y);
    *(float2*)(out + (size_t)n * 256 + coff) = r;
}

// ---------- fused GAT gather, 16 heads x 16ch, channel-half split ----------
// wave per node, half hf: heads hf*8..hf*8+7; lane owns 2 channels (float2),
// accumulation head hA = hf*8 + lane/8. Staging: chunk of 32 edges; lane
// computes w for (edge k*8 + lane/8, head hf*8 + lane%8) over k=0..3.
__global__ __launch_bounds__(256) void k_gather_h16(
    const int* __restrict__ rowptr, const int* __restrict__ col,
    const float* __restrict__ H, const float* __restrict__ als,
    const float* __restrict__ ald, const float* __restrict__ bias,
    float* __restrict__ out, int N) {
    __shared__ int s_lds[4][32];
    __shared__ float w_lds[4][32 * 8];
    int wave = threadIdx.x >> 6, lane = threadIdx.x & 63;
    int n = blockIdx.x * 4 + wave;
    if (n >= N) return;
    int hf = blockIdx.y;
    int coff = hf * 128 + lane * 2;
    int start = rowptr[n], end = rowptr[n + 1];
    int hW = (hf << 3) + (lane & 7);   // head this lane computes logits for
    int eW = lane >> 3;                // edge sub-slot 0..7
    float aldW = ald[n * 16 + hW];
    float2 acc = {0.f, 0.f};
    float swp = 0.f;                   // partial w-sum for head hW
    const float* Hh = H + coff;
    for (int base = start; base < end; base += 32) {
        int len = min(32, end - base);
        if (lane < 32) s_lds[wave][lane] = (lane < len) ? col[base + lane] : 0;
        LDS_FENCE();
#pragma unroll
        for (int k = 0; k < 4; ++k) {
            int esub = (k << 3) + eW;
            float w = 0.f;
            if (esub < len) {
                int s = s_lds[wave][esub];
                float v = als[s * 16 + hW] + aldW;
                v = v >= 0.f ? v : NEG_SLOPE * v;
                w = __expf(v);
            }
            w_lds[wave][(esub << 3) + (lane & 7)] = w;  // = k*64+lane: linear
            swp += w;
        }
        LDS_FENCE();
#pragma unroll 4
        for (int e = 0; e < len; ++e) {
            int se = s_lds[wave][e];
            float we = w_lds[wave][(e << 3) + (lane >> 3)];  // broadcast per 8 lanes
            float2 hv = *(const float2*)(Hh + (size_t)se * 256);
            acc.x = fmaf(we, hv.x, acc.x);
            acc.y = fmaf(we, hv.y, acc.y);
        }
        LDS_FENCE();
    }
    // reduce swp over lanes with equal (lane&7): lanes 0..7 then hold heads 0..7
    swp += __shfl_xor(swp, 8);
    swp += __shfl_xor(swp, 16);
    swp += __shfl_xor(swp, 32);
    float inv = 1.0f / __shfl(swp, lane >> 3);
    float2 b2v = *(const float2*)(bias + coff);
    float2 r;
    r.x = fmaxf(fmaf(acc.x, inv, b2v.x), 0.f);
    r.y = fmaxf(fmaf(acc.y, inv, b2v.y), 0.f);
    *(float2*)(out + (size_t)n * 256 + coff) = r;
}

// ---------- segmented mean-pool (batch sorted): block per (graph, quarter) ----------
__device__ __forceinline__ int lower_bound_i(const int* __restrict__ a, int n, int v) {
    int lo = 0, hi = n;
    while (lo < hi) {
        int mid = (lo + hi) >> 1;
        if (a[mid] < v) lo = mid + 1; else hi = mid;
    }
    return lo;
}

__global__ __launch_bounds__(256) void k_pool_seg(const float* __restrict__ B,
                                                  const int* __restrict__ batch,
                                                  float* __restrict__ pooled4,
                                                  float* __restrict__ cnt, int N, int G) {
    int g = blockIdx.x >> 2, seg = blockIdx.x & 3;
    int lo = lower_bound_i(batch, N, g);
    int hi = lower_bound_i(batch, N, g + 1);
    int len = hi - lo;
    int per = (len + 3) >> 2;
    int s0 = lo + seg * per;
    int s1 = min(hi, s0 + per);
    float acc = 0.f;
#pragma unroll 4
    for (int r = s0; r < s1; ++r) acc += B[(size_t)r * 256 + threadIdx.x];
    pooled4[((size_t)(seg * G + g)) * 256 + threadIdx.x] = acc;
    if (seg == 0 && threadIdx.x == 0) cnt[g] = (float)len;
}

// ---------- final linear: wave per (g,l) ----------
__global__ __launch_bounds__(256) void k_final(const float* __restrict__ pooled4,
                                               const float* __restrict__ cnt,
                                               const float* __restrict__ lw,
                                               const float* __restrict__ lb,
                                               float* __restrict__ out, int G, int L) {
    int wave = threadIdx.x >> 6, lane = threadIdx.x & 63;
    int i = blockIdx.x * 4 + wave;
    if (i >= G * L) return;
    int g = i / L, l = i - g * L;
    float4 p = {0.f, 0.f, 0.f, 0.f};
#pragma unroll
    for (int seg = 0; seg < 4; ++seg) {
        float4 q = *(const float4*)(pooled4 + ((size_t)(seg * G + g)) * 256 + lane * 4);
        p.x += q.x; p.y += q.y; p.z += q.z; p.w += q.w;
    }
    int d0 = lane * 4;
    float acc = p.x * lw[d0 * L + l] + p.y * lw[(d0 + 1) * L + l] +
                p.z * lw[(d0 + 2) * L + l] + p.w * lw[(d0 + 3) * L + l];
#pragma unroll
    for (int off = 32; off >= 1; off >>= 1) acc += __shfl_xor(acc, off);
    if (lane == 0) out[i] = acc / fmaxf(cnt[g], 1.0f) + lb[l];
}

extern "C" void kernel_launch(void* const* d_in, const int* in_sizes, int n_in,
                              void* d_out, int out_size, void* d_ws, size_t ws_size,
                              hipStream_t stream) {
    const float* x   = (const float*)d_in[0];
    const int*   ei  = (const int*)d_in[1];
    const int*   bat = (const int*)d_in[2];
    const float* W1  = (const float*)d_in[3];
    const float* as1 = (const float*)d_in[4];
    const float* ad1 = (const float*)d_in[5];
    const float* b1  = (const float*)d_in[6];
    const float* W2  = (const float*)d_in[7];
    const float* as2 = (const float*)d_in[8];
    const float* ad2 = (const float*)d_in[9];
    const float* b2  = (const float*)d_in[10];
    const float* lw  = (const float*)d_in[11];
    const float* lb  = (const float*)d_in[12];
    float* out = (float*)d_out;

    const int N = in_sizes[2];        // 10000
    const int E = in_sizes[1] / 2;    // 320000
    const int G = 64, L = 10;
    const int Etot = E + N;

    // workspace layout (floats)
    float* A    = (float*)d_ws;              // [N,256] h1 then h2
    float* B    = A + (size_t)N * 256;       // [N,256] out1 then out2
    float* als1 = B + (size_t)N * 256;       // [N,16]
    float* ald1 = als1 + (size_t)N * 16;
    float* als2 = ald1 + (size_t)N * 16;     // [N]
    float* ald2 = als2 + N;
    float* pooled4 = ald2 + N;               // [4,G,256]
    float* cnt  = pooled4 + (size_t)4 * G * 256;  // [G]
    int* counts = (int*)(cnt + G);           // [N]
    int* rowptr = counts + N;                // [N+1]
    int* cursor = rowptr + N + 1;            // [N]
    int* col    = cursor + N;                // [Etot]

    const int BS = 256;
    auto nb = [](int n, int b) { return (n + b - 1) / b; };
    int nodes4 = nb(N, 4);
    int rows32 = nb(N, 32);

    // ---- CSR build (dst-indexed) ----
    k_zero_i32<<<nb(N, BS), BS, 0, stream>>>(counts, N);
    k_count<<<nb(Etot, BS), BS, 0, stream>>>(ei, E, N, counts);
    k_scan<<<1, 1024, 0, stream>>>(counts, rowptr, N);
    k_copy_i32<<<nb(N, BS), BS, 0, stream>>>(rowptr, cursor, N);
    k_fill_csr<<<nb(Etot, BS), BS, 0, stream>>>(ei, E, N, cursor, col);

    // ---- layer 1 ----
    k_gemm_t<128><<<rows32, BS, 0, stream>>>(x, W1, A, N);
    k_logits1<<<nb(N * 16, BS), BS, 0, stream>>>(A, as1, ad1, als1, ald1, N * 16);
    k_gather_h16<<<dim3(nodes4, 2), BS, 0, stream>>>(rowptr, col, A, als1, ald1, b1, B, N);

    // ---- layer 2 ----
    k_gemm_t<256><<<rows32, BS, 0, stream>>>(B, W2, A, N);
    k_logits2<<<nodes4, BS, 0, stream>>>(A, as2, ad2, als2, ald2, N);
    k_gather_h1<<<dim3(nodes4, 2), BS, 0, stream>>>(rowptr, col, A, als2, ald2, b2, B, N);

    // ---- pool + final linear ----
    k_pool_seg<<<G * 4, BS, 0, stream>>>(B, bat, pooled4, cnt, N, G);
    k_final<<<nb(G * L, 4), BS, 0, stream>>>(pooled4, cnt, lw, lb, out, G, L);
}

// Round 5
// 296.767 us; speedup vs baseline: 1.0179x; 1.0179x over previous
//
#include <hip/hip_runtime.h>
#include <hip/hip_bf16.h>
#include <math.h>

#define NEG_SLOPE 0.2f
// wave-internal LDS ordering: each wave owns a private LDS slice, so a plain
// lgkmcnt drain orders its own ds ops; no __syncthreads (degrees diverge).
#define LDS_FENCE() asm volatile("s_waitcnt lgkmcnt(0)" ::: "memory")

// ---------- small utils ----------
__global__ void k_zero_i32(int* __restrict__ p, int n) {
    int i = blockIdx.x * blockDim.x + threadIdx.x;
    if (i < n) p[i] = 0;
}

// ---------- CSR build over dst ----------
__global__ void k_count(const int* __restrict__ ei, int E, int N, int* __restrict__ counts) {
    int e = blockIdx.x * blockDim.x + threadIdx.x;
    int Etot = E + N;
    if (e >= Etot) return;
    int d = (e < E) ? ei[E + e] : (e - E);
    atomicAdd(&counts[d], 1);
}

// single-block shuffle scan: 1024 threads, wave-scan + 16-wave prefix
__global__ __launch_bounds__(1024) void k_scan(const int* __restrict__ counts,
                                               int* __restrict__ rowptr, int N) {
    __shared__ int wsums[16];
    __shared__ int wpref[17];
    int lane = threadIdx.x & 63, wave = threadIdx.x >> 6;
    int carry = 0;
    for (int base = 0; base < N; base += 1024) {
        int i = base + threadIdx.x;
        int v = (i < N) ? counts[i] : 0;
        int x = v;
#pragma unroll
        for (int off = 1; off < 64; off <<= 1) {
            int t = __shfl_up(x, off);
            if (lane >= off) x += t;
        }
        if (lane == 63) wsums[wave] = x;
        __syncthreads();
        if (threadIdx.x == 0) {
            int acc = 0;
#pragma unroll
            for (int w = 0; w < 16; ++w) { wpref[w] = acc; acc += wsums[w]; }
            wpref[16] = acc;
        }
        __syncthreads();
        if (i < N) rowptr[i] = carry + wpref[wave] + x - v;
        carry += wpref[16];
        __syncthreads();
    }
    if (threadIdx.x == 0) rowptr[N] = carry;
}

__global__ void k_copy_i32(const int* __restrict__ src, int* __restrict__ dst, int n) {
    int i = blockIdx.x * blockDim.x + threadIdx.x;
    if (i < n) dst[i] = src[i];
}

__global__ void k_fill_csr(const int* __restrict__ ei, int E, int N,
                           int* __restrict__ cursor, int* __restrict__ col) {
    int e = blockIdx.x * blockDim.x + threadIdx.x;
    int Etot = E + N;
    if (e >= Etot) return;
    int s, d;
    if (e < E) { s = ei[e]; d = ei[E + e]; } else { s = d = e - E; }
    int pos = atomicAdd(&cursor[d], 1);
    col[pos] = s;
}

// ---------- tiled GEMM: C[n,j] = sum_k X[n,k]*W[k,j], M=256 cols ----------
// block: 512 threads = 8 waves; 16 rows. Wave ry owns rows 2ry..2ry+1 (xs
// broadcast reads), lane cx owns cols 4cx..4cx+3. 625 blocks -> ~19 waves/CU
// (the 32-row/256-thr version had 313 blocks = 12.5% occupancy, latency-bound).
template <int K>
__global__ __launch_bounds__(512) void k_gemm_t(const float* __restrict__ X,
                                                const float* __restrict__ W,
                                                float* __restrict__ C, int N) {
    __shared__ float xs[16][K];
    int t = threadIdx.x;
    int n0 = blockIdx.x * 16;
    for (int idx = t; idx < 16 * K; idx += 512) {
        int r = idx / K, k = idx - r * K;
        int n = n0 + r;
        xs[r][k] = (n < N) ? X[(size_t)n * K + k] : 0.f;
    }
    __syncthreads();
    int cx = t & 63, ry = t >> 6;
    float4 acc0 = {0.f, 0.f, 0.f, 0.f}, acc1 = {0.f, 0.f, 0.f, 0.f};
    const float* Wp = W + cx * 4;
#pragma unroll 4
    for (int k = 0; k < K; ++k) {
        float4 w4 = *(const float4*)(Wp + (size_t)k * 256);
        float x0 = xs[ry * 2][k];
        float x1 = xs[ry * 2 + 1][k];
        acc0.x = fmaf(x0, w4.x, acc0.x);
        acc0.y = fmaf(x0, w4.y, acc0.y);
        acc0.z = fmaf(x0, w4.z, acc0.z);
        acc0.w = fmaf(x0, w4.w, acc0.w);
        acc1.x = fmaf(x1, w4.x, acc1.x);
        acc1.y = fmaf(x1, w4.y, acc1.y);
        acc1.z = fmaf(x1, w4.z, acc1.z);
        acc1.w = fmaf(x1, w4.w, acc1.w);
    }
    int na = n0 + ry * 2, nbr = na + 1;
    if (na < N) *(float4*)(C + (size_t)na * 256 + cx * 4) = acc0;
    if (nbr < N) *(float4*)(C + (size_t)nbr * 256 + cx * 4) = acc1;
}

// ---------- layer-1 attention logits: thread per (n,h), ch=16 ----------
__global__ void k_logits1(const float* __restrict__ H, const float* __restrict__ a_src,
                          const float* __restrict__ a_dst, float* __restrict__ als,
                          float* __restrict__ ald, int NH) {
    int i = blockIdx.x * blockDim.x + threadIdx.x;
    if (i >= NH) return;
    int h = i & 15;
    const float4* hp = (const float4*)(H + (size_t)i * 16);
    const float4* as = (const float4*)(a_src + h * 16);
    const float4* ad = (const float4*)(a_dst + h * 16);
    float s = 0.f, d = 0.f;
#pragma unroll
    for (int q = 0; q < 4; ++q) {
        float4 hv = hp[q], sv = as[q], dv = ad[q];
        s += hv.x * sv.x + hv.y * sv.y + hv.z * sv.z + hv.w * sv.w;
        d += hv.x * dv.x + hv.y * dv.y + hv.z * dv.z + hv.w * dv.w;
    }
    als[i] = s;
    ald[i] = d;
}

// ---------- layer-2 attention logits: wave per node, D=256 ----------
__global__ __launch_bounds__(256) void k_logits2(const float* __restrict__ H,
                                                 const float* __restrict__ a_src,
                                                 const float* __restrict__ a_dst,
                                                 float* __restrict__ als,
                                                 float* __restrict__ ald, int N) {
    int wave = threadIdx.x >> 6, lane = threadIdx.x & 63;
    int n = blockIdx.x * 4 + wave;
    if (n >= N) return;
    float4 hv = *(const float4*)(H + (size_t)n * 256 + lane * 4);
    float4 sv = *(const float4*)(a_src + lane * 4);
    float4 dv = *(const float4*)(a_dst + lane * 4);
    float s = hv.x * sv.x + hv.y * sv.y + hv.z * sv.z + hv.w * sv.w;
    float d = hv.x * dv.x + hv.y * dv.y + hv.z * dv.z + hv.w * dv.w;
#pragma unroll
    for (int off = 32; off >= 1; off >>= 1) {
        s += __shfl_xor(s, off);
        d += __shfl_xor(d, off);
    }
    if (lane == 0) { als[n] = s; ald[n] = d; }
}

// ---------- fused GAT gather, 1 head, channel-half split ----------
// grid (nodes/4, 2); wave per node, lane owns 2 channels of half hf (float2).
// phase hf=0 blocks dispatch first: active H footprint 5MB -> L2-resident.
__global__ __launch_bounds__(256) void k_gather_h1(
    const int* __restrict__ rowptr, const int* __restrict__ col,
    const float* __restrict__ H, const float* __restrict__ als,
    const float* __restrict__ ald, const float* __restrict__ bias,
    float* __restrict__ out, int N) {
    __shared__ float2 sw[4][64];
    int wave = threadIdx.x >> 6, lane = threadIdx.x & 63;
    int n = blockIdx.x * 4 + wave;
    if (n >= N) return;
    int hf = blockIdx.y;
    int coff = hf * 128 + lane * 2;
    int start = rowptr[n], end = rowptr[n + 1];
    float aldv = ald[n];
    float2 acc = {0.f, 0.f};
    float swsum = 0.f;
    const float* Hh = H + coff;
    for (int base = start; base < end; base += 64) {
        int len = min(64, end - base);
        int s = 0;
        float w = 0.f;
        if (lane < len) {
            s = col[base + lane];
            float v = als[s] + aldv;
            v = v >= 0.f ? v : NEG_SLOPE * v;
            w = __expf(v);
        }
        swsum += w;
        sw[wave][lane] = make_float2(__int_as_float(s), w);
        LDS_FENCE();
#pragma unroll 4
        for (int e = 0; e < len; ++e) {
            float2 p = sw[wave][e];
            int se = __float_as_int(p.x);
            float we = p.y;
            float2 hv = *(const float2*)(Hh + (size_t)se * 256);
            acc.x = fmaf(we, hv.x, acc.x);
            acc.y = fmaf(we, hv.y, acc.y);
        }
        LDS_FENCE();
    }
#pragma unroll
    for (int off = 32; off >= 1; off >>= 1) swsum += __shfl_xor(swsum, off);
    float inv = 1.0f / swsum;
    float2 b2v = *(const float2*)(bias + coff);
    float2 r;
    r.x = fmaf(acc.x, inv, b2v.x);
    r.y = fmaf(acc.y, inv, b2v.y);
    *(float2*)(out + (size_t)n * 256 + coff) = r;
}

// ---------- fused GAT gather, 16 heads x 16ch, channel-half split ----------
// wave per node, half hf: heads hf*8..hf*8+7; lane owns 2 channels (float2),
// accumulation head hA = hf*8 + lane/8. Staging: chunk of 32 edges; lane
// computes w for (edge k*8 + lane/8, head hf*8 + lane%8) over k=0..3.
__global__ __launch_bounds__(256) void k_gather_h16(
    const int* __restrict__ rowptr, const int* __restrict__ col,
    const float* __restrict__ H, const float* __restrict__ als,
    const float* __restrict__ ald, const float* __restrict__ bias,
    float* __restrict__ out, int N) {
    __shared__ int s_lds[4][32];
    __shared__ float w_lds[4][32 * 8];
    int wave = threadIdx.x >> 6, lane = threadIdx.x & 63;
    int n = blockIdx.x * 4 + wave;
    if (n >= N) return;
    int hf = blockIdx.y;
    int coff = hf * 128 + lane * 2;
    int start = rowptr[n], end = rowptr[n + 1];
    int hW = (hf << 3) + (lane & 7);   // head this lane computes logits for
    int eW = lane >> 3;                // edge sub-slot 0..7
    float aldW = ald[n * 16 + hW];
    float2 acc = {0.f, 0.f};
    float swp = 0.f;                   // partial w-sum for head hW
    const float* Hh = H + coff;
    for (int base = start; base < end; base += 32) {
        int len = min(32, end - base);
        if (lane < 32) s_lds[wave][lane] = (lane < len) ? col[base + lane] : 0;
        LDS_FENCE();
#pragma unroll
        for (int k = 0; k < 4; ++k) {
            int esub = (k << 3) + eW;
            float w = 0.f;
            if (esub < len) {
                int s = s_lds[wave][esub];
                float v = als[s * 16 + hW] + aldW;
                v = v >= 0.f ? v : NEG_SLOPE * v;
                w = __expf(v);
            }
            w_lds[wave][(esub << 3) + (lane & 7)] = w;  // = k*64+lane: linear
            swp += w;
        }
        LDS_FENCE();
#pragma unroll 4
        for (int e = 0; e < len; ++e) {
            int se = s_lds[wave][e];
            float we = w_lds[wave][(e << 3) + (lane >> 3)];  // broadcast per 8 lanes
            float2 hv = *(const float2*)(Hh + (size_t)se * 256);
            acc.x = fmaf(we, hv.x, acc.x);
            acc.y = fmaf(we, hv.y, acc.y);
        }
        LDS_FENCE();
    }
    // reduce swp over lanes with equal (lane&7): lanes 0..7 then hold heads 0..7
    swp += __shfl_xor(swp, 8);
    swp += __shfl_xor(swp, 16);
    swp += __shfl_xor(swp, 32);
    float inv = 1.0f / __shfl(swp, lane >> 3);
    float2 b2v = *(const float2*)(bias + coff);
    float2 r;
    r.x = fmaxf(fmaf(acc.x, inv, b2v.x), 0.f);
    r.y = fmaxf(fmaf(acc.y, inv, b2v.y), 0.f);
    *(float2*)(out + (size_t)n * 256 + coff) = r;
}

// ---------- segmented mean-pool (batch sorted): block per (graph, quarter) ----------
__device__ __forceinline__ int lower_bound_i(const int* __restrict__ a, int n, int v) {
    int lo = 0, hi = n;
    while (lo < hi) {
        int mid = (lo + hi) >> 1;
        if (a[mid] < v) lo = mid + 1; else hi = mid;
    }
    return lo;
}

__global__ __launch_bounds__(256) void k_pool_seg(const float* __restrict__ B,
                                                  const int* __restrict__ batch,
                                                  float* __restrict__ pooled4,
                                                  float* __restrict__ cnt, int N, int G) {
    int g = blockIdx.x >> 2, seg = blockIdx.x & 3;
    int lo = lower_bound_i(batch, N, g);
    int hi = lower_bound_i(batch, N, g + 1);
    int len = hi - lo;
    int per = (len + 3) >> 2;
    int s0 = lo + seg * per;
    int s1 = min(hi, s0 + per);
    float acc = 0.f;
#pragma unroll 4
    for (int r = s0; r < s1; ++r) acc += B[(size_t)r * 256 + threadIdx.x];
    pooled4[((size_t)(seg * G + g)) * 256 + threadIdx.x] = acc;
    if (seg == 0 && threadIdx.x == 0) cnt[g] = (float)len;
}

// ---------- final linear: wave per (g,l) ----------
__global__ __launch_bounds__(256) void k_final(const float* __restrict__ pooled4,
                                               const float* __restrict__ cnt,
                                               const float* __restrict__ lw,
                                               const float* __restrict__ lb,
                                               float* __restrict__ out, int G, int L) {
    int wave = threadIdx.x >> 6, lane = threadIdx.x & 63;
    int i = blockIdx.x * 4 + wave;
    if (i >= G * L) return;
    int g = i / L, l = i - g * L;
    float4 p = {0.f, 0.f, 0.f, 0.f};
#pragma unroll
    for (int seg = 0; seg < 4; ++seg) {
        float4 q = *(const float4*)(pooled4 + ((size_t)(seg * G + g)) * 256 + lane * 4);
        p.x += q.x; p.y += q.y; p.z += q.z; p.w += q.w;
    }
    int d0 = lane * 4;
    float acc = p.x * lw[d0 * L + l] + p.y * lw[(d0 + 1) * L + l] +
                p.z * lw[(d0 + 2) * L + l] + p.w * lw[(d0 + 3) * L + l];
#pragma unroll
    for (int off = 32; off >= 1; off >>= 1) acc += __shfl_xor(acc, off);
    if (lane == 0) out[i] = acc / fmaxf(cnt[g], 1.0f) + lb[l];
}

extern "C" void kernel_launch(void* const* d_in, const int* in_sizes, int n_in,
                              void* d_out, int out_size, void* d_ws, size_t ws_size,
                              hipStream_t stream) {
    const float* x   = (const float*)d_in[0];
    const int*   ei  = (const int*)d_in[1];
    const int*   bat = (const int*)d_in[2];
    const float* W1  = (const float*)d_in[3];
    const float* as1 = (const float*)d_in[4];
    const float* ad1 = (const float*)d_in[5];
    const float* b1  = (const float*)d_in[6];
    const float* W2  = (const float*)d_in[7];
    const float* as2 = (const float*)d_in[8];
    const float* ad2 = (const float*)d_in[9];
    const float* b2  = (const float*)d_in[10];
    const float* lw  = (const float*)d_in[11];
    const float* lb  = (const float*)d_in[12];
    float* out = (float*)d_out;

    const int N = in_sizes[2];        // 10000
    const int E = in_sizes[1] / 2;    // 320000
    const int G = 64, L = 10;
    const int Etot = E + N;

    // workspace layout (floats)
    float* A    = (float*)d_ws;              // [N,256] h1 then h2
    float* B    = A + (size_t)N * 256;       // [N,256] out1 then out2
    float* als1 = B + (size_t)N * 256;       // [N,16]
    float* ald1 = als1 + (size_t)N * 16;
    float* als2 = ald1 + (size_t)N * 16;     // [N]
    float* ald2 = als2 + N;
    float* pooled4 = ald2 + N;               // [4,G,256]
    float* cnt  = pooled4 + (size_t)4 * G * 256;  // [G]
    int* counts = (int*)(cnt + G);           // [N]
    int* rowptr = counts + N;                // [N+1]
    int* cursor = rowptr + N + 1;            // [N]
    int* col    = cursor + N;                // [Etot]

    const int BS = 256;
    auto nb = [](int n, int b) { return (n + b - 1) / b; };
    int nodes4 = nb(N, 4);
    int rows16 = nb(N, 16);

    // ---- CSR build (dst-indexed) ----
    k_zero_i32<<<nb(N, BS), BS, 0, stream>>>(counts, N);
    k_count<<<nb(Etot, BS), BS, 0, stream>>>(ei, E, N, counts);
    k_scan<<<1, 1024, 0, stream>>>(counts, rowptr, N);
    k_copy_i32<<<nb(N, BS), BS, 0, stream>>>(rowptr, cursor, N);
    k_fill_csr<<<nb(Etot, BS), BS, 0, stream>>>(ei, E, N, cursor, col);

    // ---- layer 1 ----
    k_gemm_t<128><<<rows16, 512, 0, stream>>>(x, W1, A, N);
    k_logits1<<<nb(N * 16, BS), BS, 0, stream>>>(A, as1, ad1, als1, ald1, N * 16);
    k_gather_h16<<<dim3(nodes4, 2), BS, 0, stream>>>(rowptr, col, A, als1, ald1, b1, B, N);

    // ---- layer 2 ----
    k_gemm_t<256><<<rows16, 512, 0, stream>>>(B, W2, A, N);
    k_logits2<<<nodes4, BS, 0, stream>>>(A, as2, ad2, als2, ald2, N);
    k_gather_h1<<<dim3(nodes4, 2), BS, 0, stream>>>(rowptr, col, A, als2, ald2, b2, B, N);

    // ---- pool + final linear ----
    k_pool_seg<<<G * 4, BS, 0, stream>>>(B, bat, pooled4, cnt, N, G);
    k_final<<<nb(G * L, 4), BS, 0, stream>>>(pooled4, cnt, lw, lb, out, G, L);
}

// Round 6
// 271.625 us; speedup vs baseline: 1.1121x; 1.0926x over previous
//
#include <hip/hip_runtime.h>
#include <hip/hip_bf16.h>
#include <math.h>

#define NEG_SLOPE 0.2f
// wave-internal LDS ordering: each wave owns a private LDS slice, so a plain
// lgkmcnt drain orders its own ds ops; no __syncthreads (degrees diverge).
#define LDS_FENCE() asm volatile("s_waitcnt lgkmcnt(0)" ::: "memory")

// ---------- small utils ----------
__global__ void k_zero_i32(int* __restrict__ p, int n) {
    int i = blockIdx.x * blockDim.x + threadIdx.x;
    if (i < n) p[i] = 0;
}

// ---------- CSR build over dst ----------
__global__ void k_count(const int* __restrict__ ei, int E, int N, int* __restrict__ counts) {
    int e = blockIdx.x * blockDim.x + threadIdx.x;
    int Etot = E + N;
    if (e >= Etot) return;
    int d = (e < E) ? ei[E + e] : (e - E);
    atomicAdd(&counts[d], 1);
}

// single-block shuffle scan: 1024 threads, wave-scan + 16-wave prefix
__global__ __launch_bounds__(1024) void k_scan(const int* __restrict__ counts,
                                               int* __restrict__ rowptr, int N) {
    __shared__ int wsums[16];
    __shared__ int wpref[17];
    int lane = threadIdx.x & 63, wave = threadIdx.x >> 6;
    int carry = 0;
    for (int base = 0; base < N; base += 1024) {
        int i = base + threadIdx.x;
        int v = (i < N) ? counts[i] : 0;
        int x = v;
#pragma unroll
        for (int off = 1; off < 64; off <<= 1) {
            int t = __shfl_up(x, off);
            if (lane >= off) x += t;
        }
        if (lane == 63) wsums[wave] = x;
        __syncthreads();
        if (threadIdx.x == 0) {
            int acc = 0;
#pragma unroll
            for (int w = 0; w < 16; ++w) { wpref[w] = acc; acc += wsums[w]; }
            wpref[16] = acc;
        }
        __syncthreads();
        if (i < N) rowptr[i] = carry + wpref[wave] + x - v;
        carry += wpref[16];
        __syncthreads();
    }
    if (threadIdx.x == 0) rowptr[N] = carry;
}

__global__ void k_copy_i32(const int* __restrict__ src, int* __restrict__ dst, int n) {
    int i = blockIdx.x * blockDim.x + threadIdx.x;
    if (i < n) dst[i] = src[i];
}

__global__ void k_fill_csr(const int* __restrict__ ei, int E, int N,
                           int* __restrict__ cursor, int* __restrict__ col) {
    int e = blockIdx.x * blockDim.x + threadIdx.x;
    int Etot = E + N;
    if (e >= Etot) return;
    int s, d;
    if (e < E) { s = ei[e]; d = ei[E + e]; } else { s = d = e - E; }
    int pos = atomicAdd(&cursor[d], 1);
    col[pos] = s;
}

// ---------- LDS-staged GEMM: C[n,j] = sum_k X[n,k]*W[k,j], 256 cols total ----------
// Tile: 32 rows x 128 cols (grid.y = col half), 512 threads, BK=32.
// W chunk staged in LDS once per block (kills the per-wave L2 W re-stream that
// bound r4/r5 at ~23 TB/s); X^T staged padded [32][36] so the transposed write
// is conflict-free and the compute read is a broadcast b128.
// Per thread: 4 rows x 2 cols; per k: 1 ds_read_b64(W) + 1 b128 bcast(X) + 8 FMA.
template <int K>
__global__ __launch_bounds__(512) void k_gemm_lds(const float* __restrict__ X,
                                                  const float* __restrict__ W,
                                                  float* __restrict__ C, int N) {
    __shared__ float ws[32][128];   // [k][col-in-half]
    __shared__ float xst[32][36];   // [k][row], +4 pad: conflict-free + 16B align
    int t = threadIdx.x;
    int n0 = blockIdx.x * 32;
    int ch = blockIdx.y;
    const float* Wh = W + ch * 128;
    int lane = t & 63, wave = t >> 6;
    int r0 = wave * 4;              // this wave's 4 rows
    float2 acc[4] = {};
    int s_kr = t >> 5;              // 0..15 (staging k-row)
    int s_q  = t & 31;              // staging quad / k index
    for (int kb = 0; kb < K; kb += 32) {
        // stage W: 32 k-rows x 32 float4 (half-wave reads 512B contiguous)
        *(float4*)&ws[s_kr][s_q * 4] =
            ((const float4*)(Wh + (size_t)(kb + s_kr) * 256))[s_q];
        *(float4*)&ws[s_kr + 16][s_q * 4] =
            ((const float4*)(Wh + (size_t)(kb + s_kr + 16) * 256))[s_q];
        // stage X^T: xst[k][row] = X[n0+row][kb+k]; coalesced reads,
        // write banks (36k+row)%32 distinct per half-wave
        {
            int k = t & 31, row = t >> 5;
            int n = n0 + row;
            xst[k][row] = (n < N) ? X[(size_t)n * K + kb + k] : 0.f;
            n = n0 + row + 16;
            xst[k][row + 16] = (n < N) ? X[(size_t)n * K + kb + k] : 0.f;
        }
        __syncthreads();
#pragma unroll 4
        for (int k = 0; k < 32; ++k) {
            float2 w2 = *(const float2*)&ws[k][lane * 2];
            float4 x4 = *(const float4*)&xst[k][r0];
            acc[0].x = fmaf(x4.x, w2.x, acc[0].x);
            acc[0].y = fmaf(x4.x, w2.y, acc[0].y);
            acc[1].x = fmaf(x4.y, w2.x, acc[1].x);
            acc[1].y = fmaf(x4.y, w2.y, acc[1].y);
            acc[2].x = fmaf(x4.z, w2.x, acc[2].x);
            acc[2].y = fmaf(x4.z, w2.y, acc[2].y);
            acc[3].x = fmaf(x4.w, w2.x, acc[3].x);
            acc[3].y = fmaf(x4.w, w2.y, acc[3].y);
        }
        __syncthreads();
    }
#pragma unroll
    for (int rr = 0; rr < 4; ++rr) {
        int n = n0 + r0 + rr;
        if (n < N) *(float2*)(C + (size_t)n * 256 + ch * 128 + lane * 2) = acc[rr];
    }
}

// ---------- layer-1 attention logits: thread per (n,h), ch=16 ----------
__global__ void k_logits1(const float* __restrict__ H, const float* __restrict__ a_src,
                          const float* __restrict__ a_dst, float* __restrict__ als,
                          float* __restrict__ ald, int NH) {
    int i = blockIdx.x * blockDim.x + threadIdx.x;
    if (i >= NH) return;
    int h = i & 15;
    const float4* hp = (const float4*)(H + (size_t)i * 16);
    const float4* as = (const float4*)(a_src + h * 16);
    const float4* ad = (const float4*)(a_dst + h * 16);
    float s = 0.f, d = 0.f;
#pragma unroll
    for (int q = 0; q < 4; ++q) {
        float4 hv = hp[q], sv = as[q], dv = ad[q];
        s += hv.x * sv.x + hv.y * sv.y + hv.z * sv.z + hv.w * sv.w;
        d += hv.x * dv.x + hv.y * dv.y + hv.z * dv.z + hv.w * dv.w;
    }
    als[i] = s;
    ald[i] = d;
}

// ---------- layer-2 attention logits: wave per node, D=256 ----------
__global__ __launch_bounds__(256) void k_logits2(const float* __restrict__ H,
                                                 const float* __restrict__ a_src,
                                                 const float* __restrict__ a_dst,
                                                 float* __restrict__ als,
                                                 float* __restrict__ ald, int N) {
    int wave = threadIdx.x >> 6, lane = threadIdx.x & 63;
    int n = blockIdx.x * 4 + wave;
    if (n >= N) return;
    float4 hv = *(const float4*)(H + (size_t)n * 256 + lane * 4);
    float4 sv = *(const float4*)(a_src + lane * 4);
    float4 dv = *(const float4*)(a_dst + lane * 4);
    float s = hv.x * sv.x + hv.y * sv.y + hv.z * sv.z + hv.w * sv.w;
    float d = hv.x * dv.x + hv.y * dv.y + hv.z * dv.z + hv.w * dv.w;
#pragma unroll
    for (int off = 32; off >= 1; off >>= 1) {
        s += __shfl_xor(s, off);
        d += __shfl_xor(d, off);
    }
    if (lane == 0) { als[n] = s; ald[n] = d; }
}

// ---------- fused GAT gather, 1 head, channel-half split ----------
__global__ __launch_bounds__(256) void k_gather_h1(
    const int* __restrict__ rowptr, const int* __restrict__ col,
    const float* __restrict__ H, const float* __restrict__ als,
    const float* __restrict__ ald, const float* __restrict__ bias,
    float* __restrict__ out, int N) {
    __shared__ float2 sw[4][64];
    int wave = threadIdx.x >> 6, lane = threadIdx.x & 63;
    int n = blockIdx.x * 4 + wave;
    if (n >= N) return;
    int hf = blockIdx.y;
    int coff = hf * 128 + lane * 2;
    int start = rowptr[n], end = rowptr[n + 1];
    float aldv = ald[n];
    float2 acc = {0.f, 0.f};
    float swsum = 0.f;
    const float* Hh = H + coff;
    for (int base = start; base < end; base += 64) {
        int len = min(64, end - base);
        int s = 0;
        float w = 0.f;
        if (lane < len) {
            s = col[base + lane];
            float v = als[s] + aldv;
            v = v >= 0.f ? v : NEG_SLOPE * v;
            w = __expf(v);
        }
        swsum += w;
        sw[wave][lane] = make_float2(__int_as_float(s), w);
        LDS_FENCE();
#pragma unroll 4
        for (int e = 0; e < len; ++e) {
            float2 p = sw[wave][e];
            int se = __float_as_int(p.x);
            float we = p.y;
            float2 hv = *(const float2*)(Hh + (size_t)se * 256);
            acc.x = fmaf(we, hv.x, acc.x);
            acc.y = fmaf(we, hv.y, acc.y);
        }
        LDS_FENCE();
    }
#pragma unroll
    for (int off = 32; off >= 1; off >>= 1) swsum += __shfl_xor(swsum, off);
    float inv = 1.0f / swsum;
    float2 b2v = *(const float2*)(bias + coff);
    float2 r;
    r.x = fmaf(acc.x, inv, b2v.x);
    r.y = fmaf(acc.y, inv, b2v.y);
    *(float2*)(out + (size_t)n * 256 + coff) = r;
}

// ---------- fused GAT gather, 16 heads x 16ch, channel-half split ----------
__global__ __launch_bounds__(256) void k_gather_h16(
    const int* __restrict__ rowptr, const int* __restrict__ col,
    const float* __restrict__ H, const float* __restrict__ als,
    const float* __restrict__ ald, const float* __restrict__ bias,
    float* __restrict__ out, int N) {
    __shared__ int s_lds[4][32];
    __shared__ float w_lds[4][32 * 8];
    int wave = threadIdx.x >> 6, lane = threadIdx.x & 63;
    int n = blockIdx.x * 4 + wave;
    if (n >= N) return;
    int hf = blockIdx.y;
    int coff = hf * 128 + lane * 2;
    int start = rowptr[n], end = rowptr[n + 1];
    int hW = (hf << 3) + (lane & 7);   // head this lane computes logits for
    int eW = lane >> 3;                // edge sub-slot 0..7
    float aldW = ald[n * 16 + hW];
    float2 acc = {0.f, 0.f};
    float swp = 0.f;                   // partial w-sum for head hW
    const float* Hh = H + coff;
    for (int base = start; base < end; base += 32) {
        int len = min(32, end - base);
        if (lane < 32) s_lds[wave][lane] = (lane < len) ? col[base + lane] : 0;
        LDS_FENCE();
#pragma unroll
        for (int k = 0; k < 4; ++k) {
            int esub = (k << 3) + eW;
            float w = 0.f;
            if (esub < len) {
                int s = s_lds[wave][esub];
                float v = als[s * 16 + hW] + aldW;
                v = v >= 0.f ? v : NEG_SLOPE * v;
                w = __expf(v);
            }
            w_lds[wave][(esub << 3) + (lane & 7)] = w;  // = k*64+lane: linear
            swp += w;
        }
        LDS_FENCE();
#pragma unroll 4
        for (int e = 0; e < len; ++e) {
            int se = s_lds[wave][e];
            float we = w_lds[wave][(e << 3) + (lane >> 3)];  // broadcast per 8 lanes
            float2 hv = *(const float2*)(Hh + (size_t)se * 256);
            acc.x = fmaf(we, hv.x, acc.x);
            acc.y = fmaf(we, hv.y, acc.y);
        }
        LDS_FENCE();
    }
    swp += __shfl_xor(swp, 8);
    swp += __shfl_xor(swp, 16);
    swp += __shfl_xor(swp, 32);
    float inv = 1.0f / __shfl(swp, lane >> 3);
    float2 b2v = *(const float2*)(bias + coff);
    float2 r;
    r.x = fmaxf(fmaf(acc.x, inv, b2v.x), 0.f);
    r.y = fmaxf(fmaf(acc.y, inv, b2v.y), 0.f);
    *(float2*)(out + (size_t)n * 256 + coff) = r;
}

// ---------- segmented mean-pool (batch sorted): block per (graph, quarter) ----------
__device__ __forceinline__ int lower_bound_i(const int* __restrict__ a, int n, int v) {
    int lo = 0, hi = n;
    while (lo < hi) {
        int mid = (lo + hi) >> 1;
        if (a[mid] < v) lo = mid + 1; else hi = mid;
    }
    return lo;
}

__global__ __launch_bounds__(256) void k_pool_seg(const float* __restrict__ B,
                                                  const int* __restrict__ batch,
                                                  float* __restrict__ pooled4,
                                                  float* __restrict__ cnt, int N, int G) {
    int g = blockIdx.x >> 2, seg = blockIdx.x & 3;
    int lo = lower_bound_i(batch, N, g);
    int hi = lower_bound_i(batch, N, g + 1);
    int len = hi - lo;
    int per = (len + 3) >> 2;
    int s0 = lo + seg * per;
    int s1 = min(hi, s0 + per);
    float acc = 0.f;
#pragma unroll 4
    for (int r = s0; r < s1; ++r) acc += B[(size_t)r * 256 + threadIdx.x];
    pooled4[((size_t)(seg * G + g)) * 256 + threadIdx.x] = acc;
    if (seg == 0 && threadIdx.x == 0) cnt[g] = (float)len;
}

// ---------- final linear: wave per (g,l) ----------
__global__ __launch_bounds__(256) void k_final(const float* __restrict__ pooled4,
                                               const float* __restrict__ cnt,
                                               const float* __restrict__ lw,
                                               const float* __restrict__ lb,
                                               float* __restrict__ out, int G, int L) {
    int wave = threadIdx.x >> 6, lane = threadIdx.x & 63;
    int i = blockIdx.x * 4 + wave;
    if (i >= G * L) return;
    int g = i / L, l = i - g * L;
    float4 p = {0.f, 0.f, 0.f, 0.f};
#pragma unroll
    for (int seg = 0; seg < 4; ++seg) {
        float4 q = *(const float4*)(pooled4 + ((size_t)(seg * G + g)) * 256 + lane * 4);
        p.x += q.x; p.y += q.y; p.z += q.z; p.w += q.w;
    }
    int d0 = lane * 4;
    float acc = p.x * lw[d0 * L + l] + p.y * lw[(d0 + 1) * L + l] +
                p.z * lw[(d0 + 2) * L + l] + p.w * lw[(d0 + 3) * L + l];
#pragma unroll
    for (int off = 32; off >= 1; off >>= 1) acc += __shfl_xor(acc, off);
    if (lane == 0) out[i] = acc / fmaxf(cnt[g], 1.0f) + lb[l];
}

extern "C" void kernel_launch(void* const* d_in, const int* in_sizes, int n_in,
                              void* d_out, int out_size, void* d_ws, size_t ws_size,
                              hipStream_t stream) {
    const float* x   = (const float*)d_in[0];
    const int*   ei  = (const int*)d_in[1];
    const int*   bat = (const int*)d_in[2];
    const float* W1  = (const float*)d_in[3];
    const float* as1 = (const float*)d_in[4];
    const float* ad1 = (const float*)d_in[5];
    const float* b1  = (const float*)d_in[6];
    const float* W2  = (const float*)d_in[7];
    const float* as2 = (const float*)d_in[8];
    const float* ad2 = (const float*)d_in[9];
    const float* b2  = (const float*)d_in[10];
    const float* lw  = (const float*)d_in[11];
    const float* lb  = (const float*)d_in[12];
    float* out = (float*)d_out;

    const int N = in_sizes[2];        // 10000
    const int E = in_sizes[1] / 2;    // 320000
    const int G = 64, L = 10;
    const int Etot = E + N;

    // workspace layout (floats)
    float* A    = (float*)d_ws;              // [N,256] h1 then h2
    float* B    = A + (size_t)N * 256;       // [N,256] out1 then out2
    float* als1 = B + (size_t)N * 256;       // [N,16]
    float* ald1 = als1 + (size_t)N * 16;
    float* als2 = ald1 + (size_t)N * 16;     // [N]
    float* ald2 = als2 + N;
    float* pooled4 = ald2 + N;               // [4,G,256]
    float* cnt  = pooled4 + (size_t)4 * G * 256;  // [G]
    int* counts = (int*)(cnt + G);           // [N]
    int* rowptr = counts + N;                // [N+1]
    int* cursor = rowptr + N + 1;            // [N]
    int* col    = cursor + N;                // [Etot]

    const int BS = 256;
    auto nb = [](int n, int b) { return (n + b - 1) / b; };
    int nodes4 = nb(N, 4);
    int rows32 = nb(N, 32);

    // ---- CSR build (dst-indexed) ----
    k_zero_i32<<<nb(N, BS), BS, 0, stream>>>(counts, N);
    k_count<<<nb(Etot, BS), BS, 0, stream>>>(ei, E, N, counts);
    k_scan<<<1, 1024, 0, stream>>>(counts, rowptr, N);
    k_copy_i32<<<nb(N, BS), BS, 0, stream>>>(rowptr, cursor, N);
    k_fill_csr<<<nb(Etot, BS), BS, 0, stream>>>(ei, E, N, cursor, col);

    // ---- layer 1 ----
    k_gemm_lds<128><<<dim3(rows32, 2), 512, 0, stream>>>(x, W1, A, N);
    k_logits1<<<nb(N * 16, BS), BS, 0, stream>>>(A, as1, ad1, als1, ald1, N * 16);
    k_gather_h16<<<dim3(nodes4, 2), BS, 0, stream>>>(rowptr, col, A, als1, ald1, b1, B, N);

    // ---- layer 2 ----
    k_gemm_lds<256><<<dim3(rows32, 2), 512, 0, stream>>>(B, W2, A, N);
    k_logits2<<<nodes4, BS, 0, stream>>>(A, as2, ad2, als2, ald2, N);
    k_gather_h1<<<dim3(nodes4, 2), BS, 0, stream>>>(rowptr, col, A, als2, ald2, b2, B, N);

    // ---- pool + final linear ----
    k_pool_seg<<<G * 4, BS, 0, stream>>>(B, bat, pooled4, cnt, N, G);
    k_final<<<nb(G * L, 4), BS, 0, stream>>>(pooled4, cnt, lw, lb, out, G, L);
}